// Round 2
// baseline (154.577 us; speedup 1.0000x reference)
//
#include <hip/hip_runtime.h>

typedef _Float16 f16;
typedef __attribute__((ext_vector_type(8))) _Float16 f16x8;
typedef __attribute__((ext_vector_type(4))) float    f32x4;

#define NP 13          // products: Wn0..6 (p=0..6), Ws0..5 (p=7..12); output = outputs[7]
#define THREADS 512    // 8 waves/block
#define NBLOCKS 256
#define TILES_PER_WAVE 4   // 2048 waves * 4 tiles * 32 rows = 262144

// All MFMA conventions below are the end-to-end verified m91/m97 ones:
//   mfma_f32_16x16x32(A, B, acc): D[m][n] = sum_k A[m][k]*B[n][k]
//   A frag: lane holds A[m=lane&15][k = (lane>>4)*8 + j], j=0..7  (16B contiguous)
//   B frag: lane holds B[n=lane&15][k = (lane>>4)*8 + j]          (weight rows, row-major!)
//   C/D:    col(n)=lane&15, row(m)=(lane>>4)*4 + reg
// Orientation: y = h @ W^T  ->  A = activations (batch-major), B = W rows. Bias is a
// free accumulator splat (bias[n] with n=lane&15, same for all 4 regs).
__global__ __launch_bounds__(THREADS, 2)
void nn_fused(const float* __restrict__ x,
              const float* __restrict__ Wn, const float* __restrict__ bn,
              const float* __restrict__ Ws, const float* __restrict__ bs,
              float* __restrict__ out)
{
    __shared__ f16   w_lds[NP * 4096];   // [p][f=64][k=64] f16, 16B chunks XOR-swizzled
    __shared__ float bias_lds[NP * 64];  // fp32 biases
    __shared__ f16   act[8 * 2048];      // per-wave 32x64 f16 scratch (C->A transform)

    const int tid = threadIdx.x;

    // ---- stage weights fp32->f16 (swizzled) + biases fp32, once per block ----
    for (int c = tid; c < NP * 512; c += THREADS) {
        const int p = c >> 9, f = (c >> 3) & 63, ch = c & 7;
        const float* src = (p < 7 ? Wn + p * 4096 : Ws + (p - 7) * 4096) + f * 64 + ch * 8;
        f16x8 v;
#pragma unroll
        for (int e = 0; e < 8; ++e) v[e] = (f16)src[e];
        __builtin_memcpy(&w_lds[p * 4096 + f * 64 + ((ch ^ (f & 7)) * 8)], &v, 16);
    }
    for (int i = tid; i < NP * 64; i += THREADS) {
        const int p = i >> 6, f = i & 63;
        bias_lds[i] = (p < 7) ? bn[p * 64 + f] : bs[(p - 7) * 64 + f];
    }
    __syncthreads();   // only barrier; everything after is wave-private

    const int lane = tid & 63;
    const int wid  = tid >> 6;
    const int l15  = lane & 15;
    const int quad = lane >> 4;
    f16* awave = &act[wid * 2048];

    const int gw = blockIdx.x * (THREADS / 64) + wid;

    for (int t = 0; t < TILES_PER_WAVE; ++t) {
        const long row0 = (long)(gw + t * (NBLOCKS * THREADS / 64)) * 32;

        f16x8 Aprev[2][2], Aprev2[2][2], Anew[2][2];   // [mtile][kblock]

        // ---- x -> layer-1 A-frags (fp32 -> f16), 8 contiguous floats per frag-quad ----
#pragma unroll
        for (int mt = 0; mt < 2; ++mt)
#pragma unroll
        for (int kb = 0; kb < 2; ++kb) {
            const float* p2 = x + (row0 + mt * 16 + l15) * 64 + kb * 32 + quad * 8;
            f16x8 v;
#pragma unroll
            for (int e = 0; e < 8; ++e) v[e] = (f16)p2[e];
            Aprev[mt][kb] = v;
        }

        auto wfrag = [&](int p, int nt, int kb) -> f16x8 {
            const int f = nt * 16 + l15;                 // weight row = output feature
            const int slot = (kb * 4 + quad) ^ (f & 7);  // un-swizzle 16B chunk
            f16x8 v;
            __builtin_memcpy(&v, &w_lds[p * 4096 + f * 64 + slot * 8], 16);
            return v;
        };

        auto tileprod = [&](int p, int nt, const f16x8 A[2]) -> f32x4 {
            const float bv = bias_lds[p * 64 + nt * 16 + l15];
            f32x4 acc = {bv, bv, bv, bv};
            acc = __builtin_amdgcn_mfma_f32_16x16x32_f16(A[0], wfrag(p, nt, 0), acc, 0, 0, 0);
            acc = __builtin_amdgcn_mfma_f32_16x16x32_f16(A[1], wfrag(p, nt, 1), acc, 0, 0, 0);
            return acc;
        };

        // C-layout -> LDS (f16), swizzled to match act_read's chunk addressing
        auto act_write = [&](int mt, int nt, f32x4 v) {
            const int f = nt * 16 + l15;
#pragma unroll
            for (int r = 0; r < 4; ++r) {
                const int row = mt * 16 + quad * 4 + r;       // batch row within tile
                const int slot = (f >> 3) ^ (row & 7);
                awave[row * 64 + slot * 8 + (f & 7)] = (f16)v[r];
            }
        };

        auto act_read = [&](f16x8 A[2][2]) {
#pragma unroll
            for (int mt = 0; mt < 2; ++mt)
#pragma unroll
            for (int kb = 0; kb < 2; ++kb) {
                const int row = mt * 16 + l15;
                const int slot = (kb * 4 + quad) ^ (row & 7);
                __builtin_memcpy(&A[mt][kb], &awave[row * 64 + slot * 8], 16);
            }
        };

        // ---- layer 1: h1 = relu(x @ Wn0^T + bn0) ----
#pragma unroll
        for (int mt = 0; mt < 2; ++mt)
#pragma unroll
        for (int nt = 0; nt < 4; ++nt) {
            f32x4 a = tileprod(0, nt, Aprev[mt]);
            f32x4 v;
#pragma unroll
            for (int r = 0; r < 4; ++r) v[r] = fmaxf(a[r], 0.f);
            act_write(mt, nt, v);
        }
        act_read(Anew);
#pragma unroll
        for (int mt = 0; mt < 2; ++mt)
#pragma unroll
        for (int kb = 0; kb < 2; ++kb) { Aprev2[mt][kb] = Aprev[mt][kb]; Aprev[mt][kb] = Anew[mt][kb]; }

        // ---- layers 2..6: h_l = relu(h_{l-1} Wn_{l-1}^T + b) + relu(h_{l-2} Ws_{l-2}^T + b') ----
#pragma unroll
        for (int l = 2; l <= 6; ++l) {
            const int pn = l - 1, ps = 7 + (l - 2);
#pragma unroll
            for (int mt = 0; mt < 2; ++mt)
#pragma unroll
            for (int nt = 0; nt < 4; ++nt) {
                f32x4 a = tileprod(pn, nt, Aprev[mt]);
                f32x4 b = tileprod(ps, nt, Aprev2[mt]);
                f32x4 v;
#pragma unroll
                for (int r = 0; r < 4; ++r) v[r] = fmaxf(a[r], 0.f) + fmaxf(b[r], 0.f);
                act_write(mt, nt, v);
            }
            act_read(Anew);
#pragma unroll
            for (int mt = 0; mt < 2; ++mt)
#pragma unroll
            for (int kb = 0; kb < 2; ++kb) { Aprev2[mt][kb] = Aprev[mt][kb]; Aprev[mt][kb] = Anew[mt][kb]; }
        }

        // ---- layer 7: out = relu(h6 Wn6^T + bn6) + relu(h5 Ws5^T + bs5), fp32 store ----
#pragma unroll
        for (int mt = 0; mt < 2; ++mt)
#pragma unroll
        for (int nt = 0; nt < 4; ++nt) {
            f32x4 a = tileprod(6,  nt, Aprev[mt]);
            f32x4 b = tileprod(12, nt, Aprev2[mt]);
            const int f = nt * 16 + l15;
#pragma unroll
            for (int r = 0; r < 4; ++r) {
                out[(row0 + mt * 16 + quad * 4 + r) * 64 + f] = fmaxf(a[r], 0.f) + fmaxf(b[r], 0.f);
            }
        }
    }
}

extern "C" void kernel_launch(void* const* d_in, const int* in_sizes, int n_in,
                              void* d_out, int out_size, void* d_ws, size_t ws_size,
                              hipStream_t stream) {
    (void)in_sizes; (void)n_in; (void)d_ws; (void)ws_size; (void)out_size;
    const float* x  = (const float*)d_in[0];
    const float* Wn = (const float*)d_in[1];
    const float* bn = (const float*)d_in[2];
    const float* Ws = (const float*)d_in[3];
    const float* bs = (const float*)d_in[4];
    nn_fused<<<dim3(NBLOCKS), dim3(THREADS), 0, stream>>>(x, Wn, bn, Ws, bs, (float*)d_out);
}